// Round 1
// baseline (287.433 us; speedup 1.0000x reference)
//
#include <hip/hip_runtime.h>
#include <cstdint>
#include <cstddef>

#define B_   2048
#define L_   13
#define H_   768
#define NROW (B_ * L_)          // 26624 flattened hidden rows
#define RTEMP 20.0f             // 1 / 0.05

typedef short bf16x8 __attribute__((ext_vector_type(8)));  // 8 bf16 in 4 VGPRs (guide §3)
typedef float f32x4  __attribute__((ext_vector_type(4)));

__device__ __forceinline__ float bf2f(unsigned short u) {
  union { unsigned int i; float f; } v; v.i = ((unsigned int)u) << 16; return v.f;
}
__device__ __forceinline__ unsigned short f2bf(float f) {
  union { float f; unsigned int i; } v; v.f = f;
  unsigned int r = v.i + 0x7fffu + ((v.i >> 16) & 1u);   // RNE
  return (unsigned short)(r >> 16);
}

// async global->LDS, 16B per lane (guide §5: width=16 is the big lever)
__device__ __forceinline__ void llds16(const void* g, void* l) {
  __builtin_amdgcn_global_load_lds(
      (const __attribute__((address_space(1))) void*)g,
      (__attribute__((address_space(3))) void*)l,
      16, 0, 0);
}

// ---------------------------------------------------------------------------
// Kernel 1: L2-normalize rows of cls and hidden, cast to bf16.
// rows [0, B_) -> cls, rows [B_, B_+NROW) -> hidden. 768 = 256 threads x 3.
// ---------------------------------------------------------------------------
__global__ __launch_bounds__(256) void k_normalize(
    const float* __restrict__ cls, const float* __restrict__ hidden,
    unsigned short* __restrict__ cn, unsigned short* __restrict__ hn)
{
  const int row = blockIdx.x;
  const int t = threadIdx.x;
  const float* src;
  unsigned short* dst;
  if (row < B_) { src = cls + (size_t)row * H_;        dst = cn + (size_t)row * H_; }
  else          { src = hidden + (size_t)(row - B_) * H_; dst = hn + (size_t)(row - B_) * H_; }

  float x0 = src[t], x1 = src[t + 256], x2 = src[t + 512];
  float ss = x0 * x0 + x1 * x1 + x2 * x2;
#pragma unroll
  for (int m = 1; m < 64; m <<= 1) ss += __shfl_xor(ss, m);
  __shared__ float wss[4];
  if ((t & 63) == 0) wss[t >> 6] = ss;
  __syncthreads();
  float tot = wss[0] + wss[1] + wss[2] + wss[3];
  float scale = 1.0f / fmaxf(sqrtf(tot), 1e-8f);   // matches ref: x / max(||x||, eps)
  dst[t]       = f2bf(x0 * scale);
  dst[t + 256] = f2bf(x1 * scale);
  dst[t + 512] = f2bf(x2 * scale);
}

// ---------------------------------------------------------------------------
// Kernel 2: C = cn @ hn^T, fused exp(20*c) + row-sum -> atomicAdd S_all[row].
// m97 structure: 128x128 tile, BK=32, 4 waves, 16x16x32 bf16 MFMA,
// global_load_lds width=16 staging, 2 barriers per K-step.
// Grid: (NROW/128, B_/128) = (208, 16).
// ---------------------------------------------------------------------------
__global__ __launch_bounds__(256) void k_gemm_expsum(
    const unsigned short* __restrict__ cn,
    const unsigned short* __restrict__ hn,
    float* __restrict__ S_all)
{
  __shared__ __align__(16) unsigned short lA[128 * 32];  // [row][k] 8KB
  __shared__ __align__(16) unsigned short lB[128 * 32];  // [col][k] 8KB (hn is B^T layout)

  const int tid  = threadIdx.x;
  const int lane = tid & 63;
  const int wave = tid >> 6;
  const size_t brow = (size_t)blockIdx.y * 128;   // over M = 2048
  const size_t bcol = (size_t)blockIdx.x * 128;   // over N = 26624

  f32x4 acc[4][4] = {};

  // staging map: thread t covers LDS bytes [t*16, t*16+16) and +4096.
  // LDS byte t*16 -> row t/4, k-bytes (t%4)*16 .. +16  (row = 64B in LDS)
  const int srow = tid >> 2;
  const int skb  = (tid & 3) << 4;
  const size_t rs = (size_t)H_ * 2;               // global row stride bytes (1536)
  const char* gA = (const char*)cn + (brow + srow) * rs + skb;
  const char* gB = (const char*)hn + (bcol + srow) * rs + skb;
  char* lAp = (char*)lA + tid * 16;
  char* lBp = (char*)lB + tid * 16;

  const int wr = (wave >> 1) << 6;   // wave row base (0/64)
  const int wc = (wave & 1) << 6;    // wave col base (0/64)
  const int fr = lane & 15;
  const int kf = (lane >> 4) << 3;   // k element offset 0/8/16/24

  for (int k0 = 0; k0 < H_; k0 += 32) {
    const int kb = k0 * 2;
    llds16(gA + kb,           lAp);
    llds16(gA + 64 * rs + kb, lAp + 4096);
    llds16(gB + kb,           lBp);
    llds16(gB + 64 * rs + kb, lBp + 4096);
    __syncthreads();   // drains vmcnt: staged data visible

    bf16x8 afrag[4], bfrag[4];
#pragma unroll
    for (int mi = 0; mi < 4; mi++)
      afrag[mi] = *(const bf16x8*)&lA[(wr + mi * 16 + fr) * 32 + kf];
#pragma unroll
    for (int ni = 0; ni < 4; ni++)
      bfrag[ni] = *(const bf16x8*)&lB[(wc + ni * 16 + fr) * 32 + kf];
#pragma unroll
    for (int mi = 0; mi < 4; mi++)
#pragma unroll
      for (int ni = 0; ni < 4; ni++)
        acc[mi][ni] = __builtin_amdgcn_mfma_f32_16x16x32_bf16(
            afrag[mi], bfrag[ni], acc[mi][ni], 0, 0, 0);
    __syncthreads();   // compute done before next stage overwrites LDS
  }

  // Epilogue: D row = wr + mi*16 + (lane>>4)*4 + j, col = wc + ni*16 + (lane&15)
  // (C/D layout m89-verified). exp then reduce over this wave's 64 cols.
  const int g = lane >> 4;
#pragma unroll
  for (int mi = 0; mi < 4; mi++) {
#pragma unroll
    for (int j = 0; j < 4; j++) {
      float v = __expf(RTEMP * acc[mi][0][j]) + __expf(RTEMP * acc[mi][1][j]) +
                __expf(RTEMP * acc[mi][2][j]) + __expf(RTEMP * acc[mi][3][j]);
      v += __shfl_xor(v, 1);
      v += __shfl_xor(v, 2);
      v += __shfl_xor(v, 4);
      v += __shfl_xor(v, 8);   // 16-lane col-group reduce (same row across fr)
      if (fr == 0)
        atomicAdd(&S_all[brow + wr + mi * 16 + g * 4 + j], v);
    }
  }
}

// ---------------------------------------------------------------------------
// Kernel 3: per row i — 13 aligned dots (hn rows i*13+l) and 13 excluded dots
// (hn rows i + j*2048, from mask quirk c % B == i), then loss terms.
// loss_i = sum_l [ log(exp(20*d_al) + s_i) - 20*d_al ],  s_i = S_all[i] - E_i.
// ---------------------------------------------------------------------------
__global__ __launch_bounds__(256) void k_finalize(
    const unsigned short* __restrict__ cn,
    const unsigned short* __restrict__ hn,
    const float* __restrict__ S_all,
    float* __restrict__ out)
{
  const int i = blockIdx.x;
  const int t = threadIdx.x;
  const unsigned short* crow = cn + (size_t)i * H_;
  const float c0 = bf2f(crow[t]), c1 = bf2f(crow[t + 256]), c2 = bf2f(crow[t + 512]);

  __shared__ float dots[26];
  __shared__ float red[4];
  for (int r = 0; r < 26; r++) {
    size_t hrow = (r < 13) ? ((size_t)i * L_ + r)
                           : ((size_t)i + (size_t)(r - 13) * B_);
    const unsigned short* h = hn + hrow * H_;
    float d = c0 * bf2f(h[t]) + c1 * bf2f(h[t + 256]) + c2 * bf2f(h[t + 512]);
#pragma unroll
    for (int m = 1; m < 64; m <<= 1) d += __shfl_xor(d, m);
    if ((t & 63) == 0) red[t >> 6] = d;
    __syncthreads();
    if (t == 0) dots[r] = red[0] + red[1] + red[2] + red[3];
    __syncthreads();
  }
  if (t == 0) {
    float E = 0.0f;
#pragma unroll
    for (int j = 0; j < 13; j++) E += __expf(RTEMP * dots[13 + j]);
    float s = S_all[i] - E;
    float acc = 0.0f;
#pragma unroll
    for (int l = 0; l < 13; l++) {
      float d = dots[l];
      acc += logf(__expf(RTEMP * d) + s) - RTEMP * d;
    }
    atomicAdd(out, acc * (1.0f / (float)(B_ * L_)));
  }
}

// ---------------------------------------------------------------------------
extern "C" void kernel_launch(void* const* d_in, const int* in_sizes, int n_in,
                              void* d_out, int out_size, void* d_ws, size_t ws_size,
                              hipStream_t stream) {
  const float* cls    = (const float*)d_in[0];
  const float* hidden = (const float*)d_in[1];
  float* out = (float*)d_out;

  // ws layout: hn_bf16 (40,894,464 B) | cn_bf16 (3,145,728 B) | S_all (8192 B)
  char* ws = (char*)d_ws;
  unsigned short* hn = (unsigned short*)ws;
  unsigned short* cn = (unsigned short*)(ws + (size_t)NROW * H_ * 2);
  float* S_all = (float*)(ws + (size_t)NROW * H_ * 2 + (size_t)B_ * H_ * 2);

  hipMemsetAsync(S_all, 0, B_ * sizeof(float), stream);
  hipMemsetAsync(out, 0, sizeof(float), stream);

  k_normalize<<<B_ + NROW, 256, 0, stream>>>(cls, hidden, cn, hn);
  k_gemm_expsum<<<dim3(NROW / 128, B_ / 128), 256, 0, stream>>>(cn, hn, S_all);
  k_finalize<<<B_, 256, 0, stream>>>(cn, hn, S_all, out);
}

// Round 2
// 163.894 us; speedup vs baseline: 1.7538x; 1.7538x over previous
//
#include <hip/hip_runtime.h>
#include <cstdint>
#include <cstddef>

#define B_    2048
#define L_    13
#define H_    768
#define NROW  (B_ * L_)          // 26624 flattened hidden rows
#define RTEMP 20.0f              // 1 / 0.05
#define NT    24                 // K tiles: 768 / 32
#define RS    1536               // global row stride bytes (H_ * 2)

typedef short bf16x8 __attribute__((ext_vector_type(8)));
typedef float f32x4  __attribute__((ext_vector_type(4)));

static __device__ __forceinline__ unsigned short f2bf(float f) {
  union { float f; unsigned int i; } v; v.f = f;
  unsigned int r = v.i + 0x7fffu + ((v.i >> 16) & 1u);   // RNE
  return (unsigned short)(r >> 16);
}
static __device__ __forceinline__ unsigned int pack2(float a, float b) {
  return ((unsigned int)f2bf(b) << 16) | (unsigned int)f2bf(a);
}

__device__ __forceinline__ void llds16(const void* g, void* l) {
  __builtin_amdgcn_global_load_lds(
      (const __attribute__((address_space(1))) void*)g,
      (__attribute__((address_space(3))) void*)l, 16, 0, 0);
}

// ---------------------------------------------------------------------------
// Kernel 1: L2-normalize rows, cast to bf16. One wave per row, 4 rows/block.
// float4 loads (16B/lane), uint2 bf16-packed stores, shfl-only reduction.
// ---------------------------------------------------------------------------
__global__ __launch_bounds__(256) void k_normalize(
    const float* __restrict__ cls, const float* __restrict__ hidden,
    unsigned short* __restrict__ cn, unsigned short* __restrict__ hn)
{
  const int wid = threadIdx.x >> 6, lane = threadIdx.x & 63;
  const int row = blockIdx.x * 4 + wid;
  const float4* src; unsigned short* dst;
  if (row < B_) { src = (const float4*)(cls + (size_t)row * H_);          dst = cn + (size_t)row * H_; }
  else          { src = (const float4*)(hidden + (size_t)(row - B_) * H_); dst = hn + (size_t)(row - B_) * H_; }

  float4 x0 = src[lane], x1 = src[lane + 64], x2 = src[lane + 128];
  float ss = x0.x*x0.x + x0.y*x0.y + x0.z*x0.z + x0.w*x0.w
           + x1.x*x1.x + x1.y*x1.y + x1.z*x1.z + x1.w*x1.w
           + x2.x*x2.x + x2.y*x2.y + x2.z*x2.z + x2.w*x2.w;
#pragma unroll
  for (int m = 1; m < 64; m <<= 1) ss += __shfl_xor(ss, m);
  const float sc = 1.0f / fmaxf(sqrtf(ss), 1e-8f);

  uint2* d2 = (uint2*)dst;
  uint2 p;
  p.x = pack2(x0.x * sc, x0.y * sc); p.y = pack2(x0.z * sc, x0.w * sc); d2[lane]       = p;
  p.x = pack2(x1.x * sc, x1.y * sc); p.y = pack2(x1.z * sc, x1.w * sc); d2[lane + 64]  = p;
  p.x = pack2(x2.x * sc, x2.y * sc); p.y = pack2(x2.z * sc, x2.w * sc); d2[lane + 128] = p;
}

// ---------------------------------------------------------------------------
// Kernel 2: C = cn @ hn^T with fused exp/mask/row-sum epilogue.
// BM=BN=128, BK=32, 4 waves (2x2), 3-stage pipeline, 3x16KB LDS buffers.
// Raw s_barrier + counted vmcnt(4) (never drains the staging queue in the
// main loop). Conflict-free paired-row XOR swizzle:
//   lds_byte(r,slot) = (r>>1)*128 + ((slot ^ ((r>>1)&7)) << 4),
//   where slot = k16 | ((r&1)<<2); applied as pre-swizzled global source
//   (linear global_load_lds dest) + swizzled ds_read address.
// Epilogue: skip masked cols (col%2048==row) in the sum; store raw aligned
// dots (col in [13row,13row+13)) to alignedD.
// ---------------------------------------------------------------------------
__global__ __launch_bounds__(256, 2) void k_gemm(
    const unsigned short* __restrict__ cn,
    const unsigned short* __restrict__ hn,
    float* __restrict__ S_all,
    float* __restrict__ alignedD)
{
  __shared__ __align__(16) char lds[49152];   // 3 x (A 8KB | B 8KB)

  const int tid  = threadIdx.x;
  const int lane = tid & 63;
  const int wid  = tid >> 6;

  // bijective XCD swizzle: 3328 blocks = 8 * 416
  int wg = blockIdx.x;
  wg = (wg & 7) * 416 + (wg >> 3);
  const int brow = (wg / 208) * 128;      // M-panel (cls rows)
  const int bcol = (wg % 208) * 128;      // N-panel (hidden rows)

  // --- staging map: LDS linear byte o = tid*16 (+4096/round); inverse-swizzled
  // global source so that swizzled reads see the right data.
  const int slot_un = (tid & 7) ^ ((tid >> 3) & 7);
  const int srow = 2 * (tid >> 3) + (slot_un >> 2);
  const int scb  = (slot_un & 3) << 4;
  const char* gA = (const char*)cn + (size_t)(brow + srow) * RS + scb;
  const char* gB = (const char*)hn + (size_t)(bcol + srow) * RS + scb;

#define STAGE(t, bb) do {                                    \
    char* d_ = lds + (bb) + tid * 16;                        \
    llds16(gA + (t) * 64,           d_);                     \
    llds16(gA + 64 * RS + (t) * 64, d_ + 4096);              \
    llds16(gB + (t) * 64,           d_ + 8192);              \
    llds16(gB + 64 * RS + (t) * 64, d_ + 12288);             \
  } while (0)

  // --- fragment read addresses (constant per thread, +1024B per frag step)
  const int wm = wid >> 1, wn = wid & 1;
  const int fr = lane & 15, q = lane >> 4;
  const int swz  = ((q | ((fr & 1) << 2)) ^ ((fr >> 1) & 7)) << 4;
  const int offA = (wm * 32 + (fr >> 1)) * 128 + swz;
  const int offB = 8192 + (wn * 32 + (fr >> 1)) * 128 + swz;

  f32x4 acc[4][4] = {};

  // prologue: tiles 0,1 in flight (8 loads)
  STAGE(0, 0);
  STAGE(1, 16384);

  int baseR = 0;
  for (int t = 0; t < NT; ++t) {
    // WAR: my reads of the buffer about to be restaged are complete
    asm volatile("s_waitcnt lgkmcnt(0)" ::: "memory");
    // RAW: my stages for tile t have landed (tile t+1's 4 may stay in flight)
    if (t < NT - 1) asm volatile("s_waitcnt vmcnt(4)" ::: "memory");
    else            asm volatile("s_waitcnt vmcnt(0)" ::: "memory");
    __builtin_amdgcn_s_barrier();
    asm volatile("" ::: "memory");          // no LDS read hoists above barrier

    if (t + 2 < NT) {
      int baseS = baseR + 32768; if (baseS >= 49152) baseS -= 49152;
      STAGE(t + 2, baseS);
    }

    const char* bb = lds + baseR;
    bf16x8 af[4], bfr[4];
#pragma unroll
    for (int mi = 0; mi < 4; mi++) af[mi]  = *(const bf16x8*)(bb + offA + mi * 1024);
#pragma unroll
    for (int ni = 0; ni < 4; ni++) bfr[ni] = *(const bf16x8*)(bb + offB + ni * 1024);

    __builtin_amdgcn_s_setprio(1);
#pragma unroll
    for (int mi = 0; mi < 4; mi++)
#pragma unroll
      for (int ni = 0; ni < 4; ni++)
        acc[mi][ni] = __builtin_amdgcn_mfma_f32_16x16x32_bf16(
            af[mi], bfr[ni], acc[mi][ni], 0, 0, 0);
    __builtin_amdgcn_s_setprio(0);

    baseR += 16384; if (baseR >= 49152) baseR = 0;
  }
#undef STAGE

  // --- epilogue: C/D layout (m89): frag row = q*4+j, col = fr.
  const int rowb = brow + wm * 64;
  const int colb = bcol + wn * 64;
#pragma unroll
  for (int mi = 0; mi < 4; mi++) {
#pragma unroll
    for (int j = 0; j < 4; j++) {
      const int grow = rowb + mi * 16 + q * 4 + j;
      float v = 0.f;
#pragma unroll
      for (int ni = 0; ni < 4; ni++) {
        const int gcol = colb + ni * 16 + fr;
        const float a = acc[mi][ni][j];
        if ((unsigned)(gcol - grow * 13) < 13u) alignedD[gcol] = a;  // raw dot
        v += ((gcol & 2047) == grow) ? 0.f : __expf(RTEMP * a);     // masked sum
      }
      v += __shfl_xor(v, 1); v += __shfl_xor(v, 2);
      v += __shfl_xor(v, 4); v += __shfl_xor(v, 8);
      if (fr == 0) atomicAdd(&S_all[grow], v);
    }
  }
}

// ---------------------------------------------------------------------------
// Kernel 3: per row i: loss_i = sum_l [ log(exp(20 d_l) + s_i) - 20 d_l ].
// ---------------------------------------------------------------------------
__global__ __launch_bounds__(256) void k_finalize(
    const float* __restrict__ S_all, const float* __restrict__ alignedD,
    float* __restrict__ out)
{
  const int i = blockIdx.x * 256 + threadIdx.x;
  const int lane = threadIdx.x & 63, wid = threadIdx.x >> 6;
  const float s = S_all[i];
  float accv = 0.f;
#pragma unroll
  for (int l = 0; l < L_; l++) {
    const float d = RTEMP * alignedD[i * L_ + l];
    accv += logf(__expf(d) + s) - d;
  }
#pragma unroll
  for (int m = 1; m < 64; m <<= 1) accv += __shfl_xor(accv, m);
  __shared__ float wsum[4];
  if (lane == 0) wsum[wid] = accv;
  __syncthreads();
  if (threadIdx.x == 0)
    atomicAdd(out, (wsum[0] + wsum[1] + wsum[2] + wsum[3]) * (1.0f / (float)(B_ * L_)));
}

// ---------------------------------------------------------------------------
extern "C" void kernel_launch(void* const* d_in, const int* in_sizes, int n_in,
                              void* d_out, int out_size, void* d_ws, size_t ws_size,
                              hipStream_t stream) {
  const float* cls    = (const float*)d_in[0];
  const float* hidden = (const float*)d_in[1];
  float* out = (float*)d_out;

  // ws: hn bf16 (40,894,464) | cn bf16 (3,145,728) | S_all (8,192) | alignedD (106,496)
  char* ws = (char*)d_ws;
  unsigned short* hn = (unsigned short*)ws;
  unsigned short* cn = (unsigned short*)(ws + (size_t)NROW * H_ * 2);
  float* S_all    = (float*)(ws + (size_t)NROW * H_ * 2 + (size_t)B_ * H_ * 2);
  float* alignedD = (float*)(ws + (size_t)NROW * H_ * 2 + (size_t)B_ * H_ * 2 + B_ * sizeof(float));

  hipMemsetAsync(S_all, 0, B_ * sizeof(float), stream);
  hipMemsetAsync(out, 0, sizeof(float), stream);

  k_normalize<<<(B_ + NROW) / 4, 256, 0, stream>>>(cls, hidden, cn, hn);
  k_gemm<<<16 * 208, 256, 0, stream>>>(cn, hn, S_all, alignedD);
  k_finalize<<<B_ / 256, 256, 0, stream>>>(S_all, alignedD, out);
}